// Round 13
// baseline (440.513 us; speedup 1.0000x reference)
//
#include <hip/hip_runtime.h>

// Problem constants: B=8, N=2048, C=768, H=12, D=64
#define SEQ   2048
#define NH    12
#define HD    64
#define CDIM  768

typedef _Float16 half8  __attribute__((ext_vector_type(8)));
typedef _Float16 half4v __attribute__((ext_vector_type(4)));
typedef __fp16   fp16x2 __attribute__((ext_vector_type(2)));   // cvt_pkrtz native type
typedef float    f32x4  __attribute__((ext_vector_type(4)));

// 0.125 * log2(e): QK^T scores come out in log2 units -> softmax via exp2 (no mul)
#define QSCALE 0.18033688011112042f

__device__ __forceinline__ void load_lds16(const _Float16* g, _Float16* l) {
  __builtin_amdgcn_global_load_lds(
      (const __attribute__((address_space(1))) void*)g,
      (__attribute__((address_space(3))) void*)l, 16, 0, 0);
}

// ---------------- fp32 -> fp16 convert ----------------
__global__ void cvt_f32_f16(const float* __restrict__ in, _Float16* __restrict__ out, int n) {
  int i = (blockIdx.x * 256 + threadIdx.x) * 4;
  if (i >= n) return;
  float4 v = *(const float4*)(in + i);
  half4v o;
  o.x = (_Float16)v.x; o.y = (_Float16)v.y; o.z = (_Float16)v.z; o.w = (_Float16)v.w;
  *(half4v*)(out + i) = o;
}

// ---------------- GEMM: C[r][f] = sum_k A[r][k] * W[f][k] ----------------
// MODE 0: QKV projection epilogue -> scatter q (scaled by 0.125*log2e), k to
//         [B,H,N,D], v to [B,H,D,N].  MODE 1: fp32 out[r][f] + bias[f].
template <int MODE, int GX>
__global__ __launch_bounds__(256, 2) void gemm_f16(
    const _Float16* __restrict__ A, const _Float16* __restrict__ W,
    _Float16* __restrict__ qo, _Float16* __restrict__ ko, _Float16* __restrict__ vo,
    float* __restrict__ out, const float* __restrict__ bias) {
  __shared__ __align__(16) _Float16 As[128 * 64];
  __shared__ __align__(16) _Float16 Bs[128 * 64];

  const int tid  = threadIdx.x;
  const int wave = tid >> 6;
  const int lane = tid & 63;
  const int wm = wave >> 1, wn = wave & 1;
  const int l15 = lane & 15, lg = lane >> 4;

  // XCD-chunked swizzle (nwg % 8 == 0 for both launches)
  const int nwg = GX * gridDim.y;
  int id = blockIdx.y * GX + blockIdx.x;
  id = (id & 7) * (nwg >> 3) + (id >> 3);
  const int rowBase = (id / GX) * 128;
  const int colBase = (id % GX) * 128;

  const f32x4 fzero = {0.f, 0.f, 0.f, 0.f};
  f32x4 acc[4][4];
#pragma unroll
  for (int m = 0; m < 4; ++m)
#pragma unroll
    for (int n = 0; n < 4; ++n) acc[m][n] = fzero;

  for (int kt = 0; kt < CDIM; kt += 64) {
    __syncthreads();
#pragma unroll
    for (int p = 0; p < 4; ++p) {
      int c = tid + p * 256;
      int r = c >> 3, cb = (c & 7) * 8;  // 8 chunks of 16B per 64-elem row
      load_lds16(A + (size_t)(rowBase + r) * CDIM + kt + cb, As + c * 8);
      load_lds16(W + (size_t)(colBase + r) * CDIM + kt + cb, Bs + c * 8);
    }
    __syncthreads();
#pragma unroll
    for (int ks = 0; ks < 2; ++ks) {
      half8 af[4], bf[4];
#pragma unroll
      for (int m = 0; m < 4; ++m)
        af[m] = *(const half8*)(As + (wm * 64 + m * 16 + l15) * 64 + ks * 32 + lg * 8);
#pragma unroll
      for (int n = 0; n < 4; ++n)
        bf[n] = *(const half8*)(Bs + (wn * 64 + n * 16 + l15) * 64 + ks * 32 + lg * 8);
#pragma unroll
      for (int m = 0; m < 4; ++m)
#pragma unroll
        for (int n = 0; n < 4; ++n)
          acc[m][n] = __builtin_amdgcn_mfma_f32_16x16x32_f16(af[m], bf[n], acc[m][n], 0, 0, 0);
    }
  }

  // Epilogue. C/D frag: col = lane&15, row = (lane>>4)*4 + g
  if constexpr (MODE == 0) {
#pragma unroll
    for (int m = 0; m < 4; ++m) {
#pragma unroll
      for (int n = 0; n < 4; ++n) {
        int f = colBase + wn * 64 + n * 16 + l15;      // 0..2303
        int which = f / CDIM;                          // uniform per (m,n)
        int fr = f - which * CDIM;
        int h = fr >> 6, d = fr & 63;
        int r0 = rowBase + wm * 64 + m * 16 + lg * 4;  // 4 consecutive rows
        int b = r0 >> 11, nn = r0 & 2047;              // never crosses 2048
        size_t bh = (size_t)(b * NH + h);
        if (which == 2) {
          // v: [B,H,D,N] -> the 4 g-values are consecutive n -> one 8B store
          half4v vv;
#pragma unroll
          for (int g = 0; g < 4; ++g) vv[g] = (_Float16)acc[m][n][g];
          *(half4v*)(vo + ((bh * HD + d) * SEQ + nn)) = vv;
        } else {
#pragma unroll
          for (int g = 0; g < 4; ++g) {
            float v = acc[m][n][g];
            if (which == 0) qo[(bh * SEQ + nn + g) * HD + d] = (_Float16)(v * QSCALE);
            else            ko[(bh * SEQ + nn + g) * HD + d] = (_Float16)v;
          }
        }
      }
    }
  } else {
#pragma unroll
    for (int m = 0; m < 4; ++m) {
#pragma unroll
      for (int n = 0; n < 4; ++n) {
        int f = colBase + wn * 64 + n * 16 + l15;
        float bv = bias[f];
#pragma unroll
        for (int g = 0; g < 4; ++g) {
          int r = rowBase + wm * 64 + m * 16 + lg * 4 + g;
          out[(size_t)r * CDIM + f] = acc[m][n][g] + bv;
        }
      }
    }
  }
}

// ---------------- Flash attention ----------------
// block = 256 (4 waves), grid = 768. Wave owns 64 q-rows (4 sub-blocks of 16).
// ROUND-13 register diet -> __launch_bounds__(256,3) = 3 blocks/CU (12 waves):
//  - minit as scalar float[4] (C-init vector materializes into transient st)
//  - QK+exp+pack processed in qs-PAIRS: st[2][4] (32 regs) instead of
//    st[4][4] (64); pair-0's st dies into 8 pvb regs before pair-1's st is
//    born. Overflow check per-pair (while its st is live). PV unified.
//  Peak live ~165 regs <= 170 cap. Cost: K-frag reads 8->16 b128/wave-tile.
// KEY-PERMUTED K staging (round 7): concat(exp(st[2kb]),exp(st[2kb+1])) IS
// the 16x16x32 B-frag for PV. V LDS: linear rows + 3-bit XOR granule swizzle
// both sides (zero conflicts, rounds 9/11). K via global_load_lds; V
// register-staged. Softmax: C-init = -mo, ones-MFMA row sum, sum-overflow
// defer check, raw exp2, cvt_pkrtz packing.
__global__ __launch_bounds__(256, 3) void attn_f16(
    const _Float16* __restrict__ qb, const _Float16* __restrict__ kb,
    const _Float16* __restrict__ vt, _Float16* __restrict__ ob) {
  __shared__ __align__(16) _Float16 Ks[2][64 * 64];
  __shared__ __align__(16) _Float16 Vs[2][64 * 64];

  const int tid  = threadIdx.x;
  const int wave = tid >> 6;
  const int lane = tid & 63;
  const int l15 = lane & 15, lg = lane >> 4;

  // XCD-chunked mapping: xcd = i&7 owns 12 heads x all 8 q-tiles
  const int i = blockIdx.y * gridDim.x + blockIdx.x;  // 0..767
  const int w = i >> 3;                               // 0..95
  const int bh = (i & 7) * NH + (w % NH);
  const int qt = w / NH;                              // 0..7

  const _Float16* qp = qb + (size_t)bh * SEQ * HD;
  const _Float16* kp = kb + (size_t)bh * SEQ * HD;
  const _Float16* vp = vt + (size_t)bh * SEQ * HD;  // Vt: [64 d][2048 keys]

  // Q fragments (pre-scaled): B-frag n = l15 = q, k = lg*8+j
  half8 qf[4][2];
#pragma unroll
  for (int qs = 0; qs < 4; ++qs) {
    int qrow = qt * 256 + wave * 64 + qs * 16 + l15;
    qf[qs][0] = *(const half8*)(qp + (size_t)qrow * HD + lg * 8);
    qf[qs][1] = *(const half8*)(qp + (size_t)qrow * HD + 32 + lg * 8);
  }

  const f32x4 fzero = {0.f, 0.f, 0.f, 0.f};
  const _Float16 h1 = (_Float16)1.f;
  const half8 ones8 = {h1, h1, h1, h1, h1, h1, h1, h1};
  f32x4 o[4][4];
#pragma unroll
  for (int qs = 0; qs < 4; ++qs)
#pragma unroll
    for (int dt = 0; dt < 4; ++dt) o[qs][dt] = fzero;
  float mneg[4] = {0.f, 0.f, 0.f, 0.f};  // = -mo (log2), scalar per-query
  float ls[4] = {0.f, 0.f, 0.f, 0.f};    // exact per-query sums

  // staging: 256 threads cover the 512 16B chunks of each tile in TWO
  // chunk-sets; within each set a wave's lanes are 16B-contiguous (DMA rule).
  const int c0 = wave * 128 + lane, c1 = c0 + 64;
  const int r0_ = c0 >> 3, sa0 = c0 & 7;
  const int r1_ = c1 >> 3, sa1 = c1 & 7;
  auto kpermf = [](int r) {
    int t = r >> 4, m = r & 15;
    return ((t >> 1) << 5) + ((m >> 2) << 3) + ((t & 1) << 2) + (m & 3);
  };
  const int kg0 = kpermf(r0_) * HD + (((sa0 * 16) ^ ((r0_ & 7) << 4)) >> 1);
  const int kg1 = kpermf(r1_) * HD + (((sa1 * 16) ^ ((r1_ & 7) << 4)) >> 1);
  const int vg0 = r0_ * SEQ + sa0 * 8;
  const int vg1 = r1_ * SEQ + sa1 * 8;
  _Float16* const ksd0 = (_Float16*)Ks + (size_t)c0 * 8;   // + buf*4096
  _Float16* const ksd1 = (_Float16*)Ks + (size_t)c1 * 8;
  _Float16* const vd0 = (_Float16*)Vs + r0_ * 64 + ((sa0 ^ (r0_ & 7)) * 8);
  _Float16* const vd1 = (_Float16*)Vs + r1_ * 64 + ((sa1 ^ (r1_ & 7)) * 8);
  uint4 vreg0, vreg1;

  auto kv_issue = [&](int dstBuf, int kt) {
    const _Float16* kt_base = kp + (size_t)kt * 64 * HD;
    load_lds16(kt_base + kg0, ksd0 + dstBuf * 4096);
    load_lds16(kt_base + kg1, ksd1 + dstBuf * 4096);
    vreg0 = *(const uint4*)(vp + vg0 + kt * 64);
    vreg1 = *(const uint4*)(vp + vg1 + kt * 64);
  };
  auto v_commit = [&](int dstBuf) {
    *(uint4*)(vd0 + dstBuf * 4096) = vreg0;
    *(uint4*)(vd1 + dstBuf * 4096) = vreg1;
  };

  kv_issue(0, 0);
  v_commit(0);
  __syncthreads();
  int buf = 0;

  const float TH = 4096.0f;  // defer window 2^12; pv <= sum <= TH fits f16
  const int NT = SEQ / 64;
  for (int kt = 0; kt < NT; ++kt) {
    if (kt + 1 < NT) kv_issue(buf ^ 1, kt + 1);  // loads in flight over compute

    half8 pvb[4][2];
#pragma unroll
    for (int pr = 0; pr < 2; ++pr) {             // qs-pairs {0,1}, {2,3}
      // ---- S^T - mo = K @ Q^T + (-mo) for this pair
      f32x4 st[2][4];
      __builtin_amdgcn_s_setprio(1);
#pragma unroll
      for (int ct = 0; ct < 4; ++ct) {
        int krow = ct * 16 + l15;
        const char* kbase = (const char*)&Ks[buf][0] + krow * 128;
        half8 kf0 = *(const half8*)(kbase + ((lg * 16) ^ ((krow & 7) << 4)));
        half8 kf1 = *(const half8*)(kbase + ((64 + lg * 16) ^ ((krow & 7) << 4)));
#pragma unroll
        for (int q2 = 0; q2 < 2; ++q2) {
          int qs = pr * 2 + q2;
          f32x4 ci = {mneg[qs], mneg[qs], mneg[qs], mneg[qs]};
          st[q2][ct] = __builtin_amdgcn_mfma_f32_16x16x32_f16(kf0, qf[qs][0], ci, 0, 0, 0);
          st[q2][ct] = __builtin_amdgcn_mfma_f32_16x16x32_f16(kf1, qf[qs][1], st[q2][ct], 0, 0, 0);
        }
      }
      __builtin_amdgcn_s_setprio(0);

      // ---- P = exp2(st), packed via v_cvt_pkrtz as PV B-frags; ones-MFMA sum
      f32x4 osum[2];
#pragma unroll
      for (int q2 = 0; q2 < 2; ++q2) {
        int qs = pr * 2 + q2;
#pragma unroll
        for (int kbk = 0; kbk < 2; ++kbk) {
          union { half8 v8; fp16x2 h2[4]; } u;
#pragma unroll
          for (int j2 = 0; j2 < 4; ++j2)
            u.h2[j2] = __builtin_amdgcn_cvt_pkrtz(
                __builtin_amdgcn_exp2f(st[q2][2 * kbk + (j2 >> 1)][(j2 & 1) * 2]),
                __builtin_amdgcn_exp2f(st[q2][2 * kbk + (j2 >> 1)][(j2 & 1) * 2 + 1]));
          pvb[qs][kbk] = u.v8;
        }
        osum[q2] = __builtin_amdgcn_mfma_f32_16x16x32_f16(ones8, pvb[qs][0], fzero, 0, 0, 0);
        osum[q2] = __builtin_amdgcn_mfma_f32_16x16x32_f16(ones8, pvb[qs][1], osum[q2], 0, 0, 0);
      }

      // ---- overflow check for this pair (st still live) -> rare fixup
      if (!__all((osum[0][0] <= TH) && (osum[1][0] <= TH))) {
#pragma unroll
        for (int q2 = 0; q2 < 2; ++q2) {
          int qs = pr * 2 + q2;
          float gm = st[q2][0][0];
#pragma unroll
          for (int ct = 0; ct < 4; ++ct)
#pragma unroll
            for (int g = 0; g < 4; ++g) gm = fmaxf(gm, st[q2][ct][g]);
          gm = fmaxf(gm, __shfl_xor(gm, 16));
          gm = fmaxf(gm, __shfl_xor(gm, 32));
          float d = fmaxf(gm, 0.0f);                    // shift so new max -> 0
          float al = __builtin_amdgcn_exp2f(-d);
          ls[qs] *= al;
#pragma unroll
          for (int dt = 0; dt < 4; ++dt) o[qs][dt] *= al;
          mneg[qs] -= d;
#pragma unroll
          for (int kbk = 0; kbk < 2; ++kbk) {
            union { half8 v8; fp16x2 h2[4]; } u;
#pragma unroll
            for (int j2 = 0; j2 < 4; ++j2)
              u.h2[j2] = __builtin_amdgcn_cvt_pkrtz(
                  __builtin_amdgcn_exp2f(st[q2][2 * kbk + (j2 >> 1)][(j2 & 1) * 2] - d),
                  __builtin_amdgcn_exp2f(st[q2][2 * kbk + (j2 >> 1)][(j2 & 1) * 2 + 1] - d));
            pvb[qs][kbk] = u.v8;
          }
          osum[q2] = __builtin_amdgcn_mfma_f32_16x16x32_f16(ones8, pvb[qs][0], fzero, 0, 0, 0);
          osum[q2] = __builtin_amdgcn_mfma_f32_16x16x32_f16(ones8, pvb[qs][1], osum[q2], 0, 0, 0);
        }
      }
      ls[pr * 2]     += osum[0][0];
      ls[pr * 2 + 1] += osum[1][0];
    }

    // ---- O^T += V @ P : V b128 frags shared across all 4 q-subs
    __builtin_amdgcn_s_setprio(1);
#pragma unroll
    for (int kbk = 0; kbk < 2; ++kbk) {
#pragma unroll
      for (int dt = 0; dt < 4; ++dt) {
        int d = dt * 16 + l15;
        half8 vf = *(const half8*)((const char*)&Vs[buf][0] + d * 128 +
                                   (((kbk * 4 + lg) ^ (d & 7)) * 16));
        o[0][dt] = __builtin_amdgcn_mfma_f32_16x16x32_f16(vf, pvb[0][kbk], o[0][dt], 0, 0, 0);
        o[1][dt] = __builtin_amdgcn_mfma_f32_16x16x32_f16(vf, pvb[1][kbk], o[1][dt], 0, 0, 0);
        o[2][dt] = __builtin_amdgcn_mfma_f32_16x16x32_f16(vf, pvb[2][kbk], o[2][dt], 0, 0, 0);
        o[3][dt] = __builtin_amdgcn_mfma_f32_16x16x32_f16(vf, pvb[3][kbk], o[3][dt], 0, 0, 0);
      }
    }
    __builtin_amdgcn_s_setprio(0);

    if (kt + 1 < NT) v_commit(buf ^ 1);  // vmcnt wait + 2x ds_write_b128
    __syncthreads();                     // drains K-DMA too
    buf ^= 1;
  }

  // epilogue: lane holds O[q = qs*16+l15][d = dt*16 + lg*4 + g]; ls is exact
  const int b = bh / NH, h = bh - b * NH;
#pragma unroll
  for (int qs = 0; qs < 4; ++qs) {
    const float inv = 1.0f / ls[qs];
    int q = qt * 256 + wave * 64 + qs * 16 + l15;
    size_t base = ((size_t)b * SEQ + q) * CDIM + h * HD;
#pragma unroll
    for (int dt = 0; dt < 4; ++dt) {
      half4v ov;
      ov.x = (_Float16)(o[qs][dt][0] * inv); ov.y = (_Float16)(o[qs][dt][1] * inv);
      ov.z = (_Float16)(o[qs][dt][2] * inv); ov.w = (_Float16)(o[qs][dt][3] * inv);
      *(half4v*)(ob + base + dt * 16 + lg * 4) = ov;
    }
  }
}

// ---------------- launch ----------------
extern "C" void kernel_launch(void* const* d_in, const int* in_sizes, int n_in,
                              void* d_out, int out_size, void* d_ws, size_t ws_size,
                              hipStream_t stream) {
  const float* x      = (const float*)d_in[0];  // [8,2048,768]
  const float* w_qkv  = (const float*)d_in[1];  // [2304,768]
  const float* w_proj = (const float*)d_in[2];  // [768,768]
  const float* b_proj = (const float*)d_in[3];  // [768]
  float* out = (float*)d_out;                   // [8,2048,768] fp32

  const size_t XN = (size_t)8 * SEQ * CDIM;     // 12,582,912
  const size_t WQ = (size_t)3 * CDIM * CDIM;    // 1,769,472
  const size_t WP = (size_t)CDIM * CDIM;        // 589,824

  _Float16* xb    = (_Float16*)d_ws;
  _Float16* wqkvb = xb + XN;
  _Float16* wpb   = wqkvb + WQ;
  _Float16* qb    = wpb + WP;
  _Float16* kb    = qb + XN;
  _Float16* vtb   = kb + XN;
  _Float16* ob    = vtb + XN;

  cvt_f32_f16<<<(int)(XN / 1024), 256, 0, stream>>>(x, xb, (int)XN);
  cvt_f32_f16<<<(int)(WQ / 1024), 256, 0, stream>>>(w_qkv, wqkvb, (int)WQ);
  cvt_f32_f16<<<(int)(WP / 1024), 256, 0, stream>>>(w_proj, wpb, (int)WP);

  // QKV: M=16384, Nf=2304  (grid 18x128 = 2304 blocks, %8==0)
  gemm_f16<0, 18><<<dim3(18, 128), 256, 0, stream>>>(
      xb, wqkvb, qb, kb, vtb, nullptr, nullptr);

  // attention: 8 q-tiles x 96 heads = 768 blocks, 256 thr (4 waves x 64 q)
  attn_f16<<<dim3(SEQ / 256, 8 * NH), 256, 0, stream>>>(qb, kb, vtb, ob);

  // proj: M=16384, Nf=768  (grid 6x128 = 768 blocks, %8==0)
  gemm_f16<1, 6><<<dim3(6, 128), 256, 0, stream>>>(
      ob, wpb, nullptr, nullptr, nullptr, out, b_proj);
}

// Round 14
// 232.330 us; speedup vs baseline: 1.8961x; 1.8961x over previous
//
#include <hip/hip_runtime.h>

// Problem constants: B=8, N=2048, C=768, H=12, D=64
#define SEQ   2048
#define NH    12
#define HD    64
#define CDIM  768

typedef _Float16 half8  __attribute__((ext_vector_type(8)));
typedef _Float16 half4v __attribute__((ext_vector_type(4)));
typedef __fp16   fp16x2 __attribute__((ext_vector_type(2)));   // cvt_pkrtz native type
typedef float    f32x4  __attribute__((ext_vector_type(4)));

// 0.125 * log2(e): QK^T scores come out in log2 units -> softmax via exp2 (no mul)
#define QSCALE 0.18033688011112042f

__device__ __forceinline__ void load_lds16(const _Float16* g, _Float16* l) {
  __builtin_amdgcn_global_load_lds(
      (const __attribute__((address_space(1))) void*)g,
      (__attribute__((address_space(3))) void*)l, 16, 0, 0);
}

// ---------------- fp32 -> fp16 convert (all three inputs, one launch) -------
// Block ranges: [0, nx) -> x, [nx, nx+nq) -> w_qkv, [nx+nq, ...) -> w_proj.
// Each block converts 1024 elements (256 thr x 4); all sizes are %1024 == 0.
__global__ void cvt_all_f16(const float* __restrict__ x, _Float16* __restrict__ xo,
                            const float* __restrict__ wq, _Float16* __restrict__ wqo,
                            const float* __restrict__ wp, _Float16* __restrict__ wpo,
                            int nxb, int nqb) {
  int bid = blockIdx.x;
  const float* in;
  _Float16* out;
  if (bid < nxb)            { in = x;  out = xo; }
  else if (bid < nxb + nqb) { in = wq; out = wqo; bid -= nxb; }
  else                      { in = wp; out = wpo; bid -= nxb + nqb; }
  int i = (bid * 256 + threadIdx.x) * 4;
  float4 v = *(const float4*)(in + i);
  half4v o;
  o.x = (_Float16)v.x; o.y = (_Float16)v.y; o.z = (_Float16)v.z; o.w = (_Float16)v.w;
  *(half4v*)(out + i) = o;
}

// ---------------- GEMM: C[r][f] = sum_k A[r][k] * W[f][k] ----------------
// MODE 0: QKV projection epilogue -> scatter q (scaled by 0.125*log2e), k to
//         [B,H,N,D], v to [B,H,D,N].  MODE 1: fp32 out[r][f] + bias[f].
template <int MODE, int GX>
__global__ __launch_bounds__(256, 2) void gemm_f16(
    const _Float16* __restrict__ A, const _Float16* __restrict__ W,
    _Float16* __restrict__ qo, _Float16* __restrict__ ko, _Float16* __restrict__ vo,
    float* __restrict__ out, const float* __restrict__ bias) {
  __shared__ __align__(16) _Float16 As[128 * 64];
  __shared__ __align__(16) _Float16 Bs[128 * 64];

  const int tid  = threadIdx.x;
  const int wave = tid >> 6;
  const int lane = tid & 63;
  const int wm = wave >> 1, wn = wave & 1;
  const int l15 = lane & 15, lg = lane >> 4;

  // XCD-chunked swizzle (nwg % 8 == 0 for both launches)
  const int nwg = GX * gridDim.y;
  int id = blockIdx.y * GX + blockIdx.x;
  id = (id & 7) * (nwg >> 3) + (id >> 3);
  const int rowBase = (id / GX) * 128;
  const int colBase = (id % GX) * 128;

  const f32x4 fzero = {0.f, 0.f, 0.f, 0.f};
  f32x4 acc[4][4];
#pragma unroll
  for (int m = 0; m < 4; ++m)
#pragma unroll
    for (int n = 0; n < 4; ++n) acc[m][n] = fzero;

  for (int kt = 0; kt < CDIM; kt += 64) {
    __syncthreads();
#pragma unroll
    for (int p = 0; p < 4; ++p) {
      int c = tid + p * 256;
      int r = c >> 3, cb = (c & 7) * 8;  // 8 chunks of 16B per 64-elem row
      load_lds16(A + (size_t)(rowBase + r) * CDIM + kt + cb, As + c * 8);
      load_lds16(W + (size_t)(colBase + r) * CDIM + kt + cb, Bs + c * 8);
    }
    __syncthreads();
#pragma unroll
    for (int ks = 0; ks < 2; ++ks) {
      half8 af[4], bf[4];
#pragma unroll
      for (int m = 0; m < 4; ++m)
        af[m] = *(const half8*)(As + (wm * 64 + m * 16 + l15) * 64 + ks * 32 + lg * 8);
#pragma unroll
      for (int n = 0; n < 4; ++n)
        bf[n] = *(const half8*)(Bs + (wn * 64 + n * 16 + l15) * 64 + ks * 32 + lg * 8);
#pragma unroll
      for (int m = 0; m < 4; ++m)
#pragma unroll
        for (int n = 0; n < 4; ++n)
          acc[m][n] = __builtin_amdgcn_mfma_f32_16x16x32_f16(af[m], bf[n], acc[m][n], 0, 0, 0);
    }
  }

  // Epilogue. C/D frag: col = lane&15, row = (lane>>4)*4 + g
  if constexpr (MODE == 0) {
#pragma unroll
    for (int m = 0; m < 4; ++m) {
#pragma unroll
      for (int n = 0; n < 4; ++n) {
        int f = colBase + wn * 64 + n * 16 + l15;      // 0..2303
        int which = f / CDIM;                          // uniform per (m,n)
        int fr = f - which * CDIM;
        int h = fr >> 6, d = fr & 63;
        int r0 = rowBase + wm * 64 + m * 16 + lg * 4;  // 4 consecutive rows
        int b = r0 >> 11, nn = r0 & 2047;              // never crosses 2048
        size_t bh = (size_t)(b * NH + h);
        if (which == 2) {
          // v: [B,H,D,N] -> the 4 g-values are consecutive n -> one 8B store
          half4v vv;
#pragma unroll
          for (int g = 0; g < 4; ++g) vv[g] = (_Float16)acc[m][n][g];
          *(half4v*)(vo + ((bh * HD + d) * SEQ + nn)) = vv;
        } else {
#pragma unroll
          for (int g = 0; g < 4; ++g) {
            float v = acc[m][n][g];
            if (which == 0) qo[(bh * SEQ + nn + g) * HD + d] = (_Float16)(v * QSCALE);
            else            ko[(bh * SEQ + nn + g) * HD + d] = (_Float16)v;
          }
        }
      }
    }
  } else {
#pragma unroll
    for (int m = 0; m < 4; ++m) {
#pragma unroll
      for (int n = 0; n < 4; ++n) {
        int f = colBase + wn * 64 + n * 16 + l15;
        float bv = bias[f];
#pragma unroll
        for (int g = 0; g < 4; ++g) {
          int r = rowBase + wm * 64 + m * 16 + lg * 4 + g;
          out[(size_t)r * CDIM + f] = acc[m][n][g] + bv;
        }
      }
    }
  }
}

// ---------------- Flash attention (round-11 structure, verified 126.9 us) ----
// block = 256 (4 waves), grid = 768 (2 blocks/CU). Wave owns 64 q-rows
// (4 sub-blocks of 16); lane owns 4 queries. __launch_bounds__(256,2):
// ~192 unified regs/wave, no spill (cap 170 or waves-6 both spill — measured).
// KEY-PERMUTED K staging (round 7): concat(exp(st[2kb]),exp(st[2kb+1])) IS
// the 16x16x32 B-frag for PV. V LDS: linear rows + 3-bit XOR granule swizzle
// both sides (zero conflicts measured). K via global_load_lds (dest =
// wave-uniform base + lane*16 per chunk-set); V register-staged.
// Softmax: C-init = -mo, ones-MFMA row sum, sum-overflow defer check, raw exp2.
__global__ __launch_bounds__(256, 2) void attn_f16(
    const _Float16* __restrict__ qb, const _Float16* __restrict__ kb,
    const _Float16* __restrict__ vt, _Float16* __restrict__ ob) {
  __shared__ __align__(16) _Float16 Ks[2][64 * 64];
  __shared__ __align__(16) _Float16 Vs[2][64 * 64];

  const int tid  = threadIdx.x;
  const int wave = tid >> 6;
  const int lane = tid & 63;
  const int l15 = lane & 15, lg = lane >> 4;

  // XCD-chunked mapping: xcd = i&7 owns 12 heads x all 8 q-tiles
  const int i = blockIdx.y * gridDim.x + blockIdx.x;  // 0..767
  const int w = i >> 3;                               // 0..95
  const int bh = (i & 7) * NH + (w % NH);
  const int qt = w / NH;                              // 0..7

  const _Float16* qp = qb + (size_t)bh * SEQ * HD;
  const _Float16* kp = kb + (size_t)bh * SEQ * HD;
  const _Float16* vp = vt + (size_t)bh * SEQ * HD;  // Vt: [64 d][2048 keys]

  // Q fragments (pre-scaled): B-frag n = l15 = q, k = lg*8+j
  half8 qf[4][2];
#pragma unroll
  for (int qs = 0; qs < 4; ++qs) {
    int qrow = qt * 256 + wave * 64 + qs * 16 + l15;
    qf[qs][0] = *(const half8*)(qp + (size_t)qrow * HD + lg * 8);
    qf[qs][1] = *(const half8*)(qp + (size_t)qrow * HD + 32 + lg * 8);
  }

  const f32x4 fzero = {0.f, 0.f, 0.f, 0.f};
  const _Float16 h1 = (_Float16)1.f;
  const half8 ones8 = {h1, h1, h1, h1, h1, h1, h1, h1};
  f32x4 o[4][4];
#pragma unroll
  for (int qs = 0; qs < 4; ++qs)
#pragma unroll
    for (int dt = 0; dt < 4; ++dt) o[qs][dt] = fzero;
  f32x4 minit[4] = {fzero, fzero, fzero, fzero};  // = -mo (log2), per-query
  float ls[4] = {0.f, 0.f, 0.f, 0.f};             // exact per-query sums

  // staging: 256 threads cover the 512 16B chunks of each tile in TWO
  // chunk-sets; within each set a wave's lanes are 16B-contiguous (DMA rule).
  const int c0 = wave * 128 + lane, c1 = c0 + 64;
  const int r0_ = c0 >> 3, sa0 = c0 & 7;
  const int r1_ = c1 >> 3, sa1 = c1 & 7;
  auto kpermf = [](int r) {
    int t = r >> 4, m = r & 15;
    return ((t >> 1) << 5) + ((m >> 2) << 3) + ((t & 1) << 2) + (m & 3);
  };
  const size_t kg0 = (size_t)kpermf(r0_) * HD + (((sa0 * 16) ^ ((r0_ & 7) << 4)) >> 1);
  const size_t kg1 = (size_t)kpermf(r1_) * HD + (((sa1 * 16) ^ ((r1_ & 7) << 4)) >> 1);
  const size_t vg0 = (size_t)r0_ * SEQ + sa0 * 8;
  const size_t vg1 = (size_t)r1_ * SEQ + sa1 * 8;
  _Float16* const ksd0 = (_Float16*)Ks + (size_t)c0 * 8;   // + buf*4096
  _Float16* const ksd1 = (_Float16*)Ks + (size_t)c1 * 8;
  _Float16* const vd0 = (_Float16*)Vs + r0_ * 64 + ((sa0 ^ (r0_ & 7)) * 8);
  _Float16* const vd1 = (_Float16*)Vs + r1_ * 64 + ((sa1 ^ (r1_ & 7)) * 8);
  uint4 vreg0, vreg1;

  auto kv_issue = [&](int dstBuf, int kt) {
    const _Float16* kt_base = kp + (size_t)kt * 64 * HD;
    load_lds16(kt_base + kg0, ksd0 + dstBuf * 4096);
    load_lds16(kt_base + kg1, ksd1 + dstBuf * 4096);
    vreg0 = *(const uint4*)(vp + vg0 + kt * 64);
    vreg1 = *(const uint4*)(vp + vg1 + kt * 64);
  };
  auto v_commit = [&](int dstBuf) {
    *(uint4*)(vd0 + dstBuf * 4096) = vreg0;
    *(uint4*)(vd1 + dstBuf * 4096) = vreg1;
  };

  kv_issue(0, 0);
  v_commit(0);
  __syncthreads();
  int buf = 0;

  const float TH = 4096.0f;  // defer window 2^12; pv <= sum <= TH fits f16
  const int NT = SEQ / 64;
  for (int kt = 0; kt < NT; ++kt) {
    if (kt + 1 < NT) kv_issue(buf ^ 1, kt + 1);  // loads in flight over compute

    // ---- S^T - mo = K @ Q^T + (-mo); K-frag reads shared across 4 q-subs
    f32x4 st[4][4];
    __builtin_amdgcn_s_setprio(1);
#pragma unroll
    for (int ct = 0; ct < 4; ++ct) {
      int krow = ct * 16 + l15;
      const char* kbase = (const char*)&Ks[buf][0] + krow * 128;
      half8 kf0 = *(const half8*)(kbase + ((lg * 16) ^ ((krow & 7) << 4)));
      half8 kf1 = *(const half8*)(kbase + ((64 + lg * 16) ^ ((krow & 7) << 4)));
#pragma unroll
      for (int qs = 0; qs < 4; ++qs) {
        st[qs][ct] = __builtin_amdgcn_mfma_f32_16x16x32_f16(kf0, qf[qs][0], minit[qs], 0, 0, 0);
        st[qs][ct] = __builtin_amdgcn_mfma_f32_16x16x32_f16(kf1, qf[qs][1], st[qs][ct], 0, 0, 0);
      }
    }
    __builtin_amdgcn_s_setprio(0);

    // ---- P = exp2(st), packed via v_cvt_pkrtz directly as PV B-frags
    half8 pvb[4][2];
    f32x4 osum[4];
#pragma unroll
    for (int qs = 0; qs < 4; ++qs) {
#pragma unroll
      for (int kbk = 0; kbk < 2; ++kbk) {
        union { half8 v8; fp16x2 h2[4]; } u;
#pragma unroll
        for (int j2 = 0; j2 < 4; ++j2)
          u.h2[j2] = __builtin_amdgcn_cvt_pkrtz(
              __builtin_amdgcn_exp2f(st[qs][2 * kbk + (j2 >> 1)][(j2 & 1) * 2]),
              __builtin_amdgcn_exp2f(st[qs][2 * kbk + (j2 >> 1)][(j2 & 1) * 2 + 1]));
        pvb[qs][kbk] = u.v8;
      }
      osum[qs] = __builtin_amdgcn_mfma_f32_16x16x32_f16(ones8, pvb[qs][0], fzero, 0, 0, 0);
      osum[qs] = __builtin_amdgcn_mfma_f32_16x16x32_f16(ones8, pvb[qs][1], osum[qs], 0, 0, 0);
    }

    // ---- overflow check on the sum (inf/NaN fail the <=) -> rare fixup
    if (!__all((osum[0][0] <= TH) && (osum[1][0] <= TH) &&
               (osum[2][0] <= TH) && (osum[3][0] <= TH))) {
#pragma unroll
      for (int qs = 0; qs < 4; ++qs) {
        float gm = st[qs][0][0];
#pragma unroll
        for (int ct = 0; ct < 4; ++ct)
#pragma unroll
          for (int g = 0; g < 4; ++g) gm = fmaxf(gm, st[qs][ct][g]);
        gm = fmaxf(gm, __shfl_xor(gm, 16));
        gm = fmaxf(gm, __shfl_xor(gm, 32));
        float d = fmaxf(gm, 0.0f);                    // shift so new max -> 0
        float al = __builtin_amdgcn_exp2f(-d);
        ls[qs] *= al;
#pragma unroll
        for (int dt = 0; dt < 4; ++dt) o[qs][dt] *= al;
        minit[qs] = minit[qs] - d;
#pragma unroll
        for (int kbk = 0; kbk < 2; ++kbk) {
          union { half8 v8; fp16x2 h2[4]; } u;
#pragma unroll
          for (int j2 = 0; j2 < 4; ++j2)
            u.h2[j2] = __builtin_amdgcn_cvt_pkrtz(
                __builtin_amdgcn_exp2f(st[qs][2 * kbk + (j2 >> 1)][(j2 & 1) * 2] - d),
                __builtin_amdgcn_exp2f(st[qs][2 * kbk + (j2 >> 1)][(j2 & 1) * 2 + 1] - d));
          pvb[qs][kbk] = u.v8;
        }
        osum[qs] = __builtin_amdgcn_mfma_f32_16x16x32_f16(ones8, pvb[qs][0], fzero, 0, 0, 0);
        osum[qs] = __builtin_amdgcn_mfma_f32_16x16x32_f16(ones8, pvb[qs][1], osum[qs], 0, 0, 0);
      }
    }
#pragma unroll
    for (int qs = 0; qs < 4; ++qs) ls[qs] += osum[qs][0];

    // ---- O^T += V @ P : V b128 frags shared across 4 q-subs
    __builtin_amdgcn_s_setprio(1);
#pragma unroll
    for (int kbk = 0; kbk < 2; ++kbk) {
#pragma unroll
      for (int dt = 0; dt < 4; ++dt) {
        int d = dt * 16 + l15;
        half8 vf = *(const half8*)((const char*)&Vs[buf][0] + d * 128 +
                                   (((kbk * 4 + lg) ^ (d & 7)) * 16));
        o[0][dt] = __builtin_amdgcn_mfma_f32_16x16x32_f16(vf, pvb[0][kbk], o[0][dt], 0, 0, 0);
        o[1][dt] = __builtin_amdgcn_mfma_f32_16x16x32_f16(vf, pvb[1][kbk], o[1][dt], 0, 0, 0);
        o[2][dt] = __builtin_amdgcn_mfma_f32_16x16x32_f16(vf, pvb[2][kbk], o[2][dt], 0, 0, 0);
        o[3][dt] = __builtin_amdgcn_mfma_f32_16x16x32_f16(vf, pvb[3][kbk], o[3][dt], 0, 0, 0);
      }
    }
    __builtin_amdgcn_s_setprio(0);

    if (kt + 1 < NT) v_commit(buf ^ 1);  // vmcnt wait + 2x ds_write_b128
    __syncthreads();                     // drains K-DMA too
    buf ^= 1;
  }

  // epilogue: lane holds O[q = qs*16+l15][d = dt*16 + lg*4 + g]; ls is exact
  const int b = bh / NH, h = bh - b * NH;
#pragma unroll
  for (int qs = 0; qs < 4; ++qs) {
    const float inv = 1.0f / ls[qs];
    int q = qt * 256 + wave * 64 + qs * 16 + l15;
    size_t base = ((size_t)b * SEQ + q) * CDIM + h * HD;
#pragma unroll
    for (int dt = 0; dt < 4; ++dt) {
      half4v ov;
      ov.x = (_Float16)(o[qs][dt][0] * inv); ov.y = (_Float16)(o[qs][dt][1] * inv);
      ov.z = (_Float16)(o[qs][dt][2] * inv); ov.w = (_Float16)(o[qs][dt][3] * inv);
      *(half4v*)(ob + base + dt * 16 + lg * 4) = ov;
    }
  }
}

// ---------------- launch ----------------
extern "C" void kernel_launch(void* const* d_in, const int* in_sizes, int n_in,
                              void* d_out, int out_size, void* d_ws, size_t ws_size,
                              hipStream_t stream) {
  const float* x      = (const float*)d_in[0];  // [8,2048,768]
  const float* w_qkv  = (const float*)d_in[1];  // [2304,768]
  const float* w_proj = (const float*)d_in[2];  // [768,768]
  const float* b_proj = (const float*)d_in[3];  // [768]
  float* out = (float*)d_out;                   // [8,2048,768] fp32

  const size_t XN = (size_t)8 * SEQ * CDIM;     // 12,582,912
  const size_t WQ = (size_t)3 * CDIM * CDIM;    // 1,769,472
  const size_t WP = (size_t)CDIM * CDIM;        // 589,824

  _Float16* xb    = (_Float16*)d_ws;
  _Float16* wqkvb = xb + XN;
  _Float16* wpb   = wqkvb + WQ;
  _Float16* qb    = wpb + WP;
  _Float16* kb    = qb + XN;
  _Float16* vtb   = kb + XN;
  _Float16* ob    = vtb + XN;

  // one fused conversion launch: 12288 + 1728 + 576 = 14592 blocks
  cvt_all_f16<<<14592, 256, 0, stream>>>(x, xb, w_qkv, wqkvb, w_proj, wpb,
                                         12288, 1728);

  // QKV: M=16384, Nf=2304  (grid 18x128 = 2304 blocks, %8==0)
  gemm_f16<0, 18><<<dim3(18, 128), 256, 0, stream>>>(
      xb, wqkvb, qb, kb, vtb, nullptr, nullptr);

  // attention: 8 q-tiles x 96 heads = 768 blocks, 256 thr (4 waves x 64 q)
  attn_f16<<<dim3(SEQ / 256, 8 * NH), 256, 0, stream>>>(qb, kb, vtb, ob);

  // proj: M=16384, Nf=768  (grid 6x128 = 768 blocks, %8==0)
  gemm_f16<1, 6><<<dim3(6, 128), 256, 0, stream>>>(
      ob, wpb, nullptr, nullptr, nullptr, out, b_proj);
}